// Round 9
// baseline (420.826 us; speedup 1.0000x reference)
//
#include <hip/hip_runtime.h>
#include <math.h>

// Problem constants: B=8, H=W=64, C=64, CI=32, SCALE=4, PATCH=3, N=256
#define BB 8

typedef __attribute__((ext_vector_type(8))) short short8;   // 8 x bf16 bits
typedef __attribute__((ext_vector_type(4))) float f32x4;

__device__ inline short f2bf(float x) {          // fp32 -> bf16 (RNE)
  unsigned u = __builtin_bit_cast(unsigned, x);
  u += 0x7fffu + ((u >> 16) & 1u);
  return (short)(u >> 16);
}
__device__ inline float bf2f(short h) {
  unsigned u = ((unsigned)(unsigned short)h) << 16;
  return __builtin_bit_cast(float, u);
}

__device__ inline void gload_lds16(const void* g, void* l) {
  __builtin_amdgcn_global_load_lds(
      (const __attribute__((address_space(1))) void*)g,
      (__attribute__((address_space(3))) void*)l, 16, 0, 0);
}

// Map ring-pixel index p (0..259) of a 66x66 frame to (row, col).
__device__ inline void ring_px(int p, int& r, int& cc) {
  if (p < 66) { r = 0; cc = p; }
  else if (p < 132) { r = 65; cc = p - 66; }
  else { int q = p - 132; r = 1 + (q >> 1); cc = (q & 1) ? 65 : 0; }
}

// ---------------- K1 (fused): blocks 0..255 = theta&g conv; 256..383 = phi+phin ----------------
__global__ __launch_bounds__(256) void k_pre(const float* __restrict__ x,
                          const float* __restrict__ theta_w, const float* __restrict__ theta_b,
                          const float* __restrict__ theta_alpha,
                          const float* __restrict__ phi_w, const float* __restrict__ phi_b,
                          const float* __restrict__ phi_alpha,
                          const float* __restrict__ g_w, const float* __restrict__ g_b,
                          const float* __restrict__ g_alpha,
                          short* __restrict__ thetaPh, short* __restrict__ thetaPl,
                          short* __restrict__ gOut,
                          short* __restrict__ Bh, short* __restrict__ Bl) {
  __shared__ __align__(16) float spool[14528];
  int tid = threadIdx.x;
  if (blockIdx.x < 256) {
    // ======== theta & g path ========
    int bid = blockIdx.x;
    int b = bid >> 5, pg = bid & 31;
    int px0 = pg * 128;
    // zero thetaP ring: 1040 short8-chunks per array per batch
    if (tid <= 32) {
      int c = pg + 32 * tid;
      if (c < 1040) {
        int p = c >> 2, off = (c & 3) * 8;
        int r, cc; ring_px(p, r, cc);
        size_t ad = ((size_t)(b * 66 + r) * 66 + cc) * 32 + off;
        short8 z = (short8)0;
        *(short8*)(thetaPh + ad) = z;
        *(short8*)(thetaPl + ad) = z;
      }
    }
    float* gw = spool;              // 64*64
    float* tw = spool + 4096;       // 64*32
    float* xs = spool + 6144;       // 64*128
    float* gb_s = spool + 14336; float* ga_s = spool + 14400;
    float* tb_s = spool + 14464; float* ta_s = spool + 14496;
    for (int idx = tid; idx < 1024; idx += 256) ((float4*)gw)[idx] = ((const float4*)g_w)[idx];
    for (int idx = tid; idx < 512; idx += 256)  ((float4*)tw)[idx] = ((const float4*)theta_w)[idx];
    if (tid < 64) { gb_s[tid] = g_b[tid]; ga_s[tid] = g_alpha[tid]; }
    else if (tid < 96) { tb_s[tid - 64] = theta_b[tid - 64]; ta_s[tid - 64] = theta_alpha[tid - 64]; }
    {
      int p = tid >> 1, half = tid & 1;
      const float* xp = x + ((size_t)b * 4096 + px0 + p) * 64 + half * 32;
      #pragma unroll
      for (int i = 0; i < 8; ++i) {
        float4 v = ((const float4*)xp)[i];
        int k = half * 32 + i * 4;
        xs[(k + 0) * 128 + p] = v.x; xs[(k + 1) * 128 + p] = v.y;
        xs[(k + 2) * 128 + p] = v.z; xs[(k + 3) * 128 + p] = v.w;
      }
    }
    __syncthreads();
    int pp = tid >> 2, q = tid & 3;
    float accg[2][16], acct[2][8];
    #pragma unroll
    for (int c = 0; c < 16; ++c) { float bv = gb_s[q * 16 + c]; accg[0][c] = bv; accg[1][c] = bv; }
    #pragma unroll
    for (int c = 0; c < 8; ++c)  { float bv = tb_s[q * 8 + c];  acct[0][c] = bv; acct[1][c] = bv; }
    for (int k = 0; k < 64; ++k) {
      float x0 = xs[k * 128 + 2 * pp], x1 = xs[k * 128 + 2 * pp + 1];
      const float* gwr = gw + k * 64 + q * 16;
      const float* twr = tw + k * 32 + q * 8;
      #pragma unroll
      for (int c = 0; c < 16; ++c) { float wv = gwr[c]; accg[0][c] += x0 * wv; accg[1][c] += x1 * wv; }
      #pragma unroll
      for (int c = 0; c < 8; ++c)  { float wv = twr[c]; acct[0][c] += x0 * wv; acct[1][c] += x1 * wv; }
    }
    #pragma unroll
    for (int e = 0; e < 2; ++e) {
      int px = px0 + 2 * pp + e;
      // g output bf16 (consumed only by gather, which converted anyway)
      short* gp = gOut + ((size_t)(b * 4096 + px)) * 64 + q * 16;
      short8 gv0, gv1;
      #pragma unroll
      for (int c = 0; c < 16; ++c) {
        float v = accg[e][c];
        float a = ga_s[q * 16 + c];
        v = v >= 0.f ? v : a * v;
        short hb = f2bf(v);
        if (c < 8) gv0[c] = hb; else gv1[c - 8] = hb;
      }
      *(short8*)(gp) = gv0;
      *(short8*)(gp + 8) = gv1;
      int h = px >> 6, w = px & 63;
      size_t off = ((size_t)(b * 66 + h + 1) * 66 + (w + 1)) * 32 + q * 8;
      short8 hv, lv;
      #pragma unroll
      for (int c = 0; c < 8; ++c) {
        float t = acct[e][c];
        float a = ta_s[q * 8 + c];
        float v = t >= 0.f ? t : a * t;
        short hi = f2bf(v);
        hv[c] = hi;
        lv[c] = f2bf(v - bf2f(hi));
      }
      *(short8*)(thetaPh + off) = hv;
      *(short8*)(thetaPl + off) = lv;
    }
  } else {
    // ======== phi + phin path: one block per (b, i-row), halo recomputed ========
    int bid = blockIdx.x - 256;
    int b = bid >> 4, irow = bid & 15;
    float* pw   = spool;            // 64*32
    float* pb   = spool + 2048;     // 32
    float* pa   = spool + 2080;     // 32
    float* ph_s = spool + 2112;     // 48*33
    float* ss2  = spool + 3696;     // 48
    float* ssp  = spool + 3744;     // 192
    for (int idx = tid; idx < 512; idx += 256) ((float4*)pw)[idx] = ((const float4*)phi_w)[idx];
    if (tid < 32) { pb[tid] = phi_b[tid]; pa[tid] = phi_alpha[tid]; }
    __syncthreads();
    // conv: threads t = lr*64 + j*4 + cg  (lr<3, j<16, cg<4 -> 8 channels each)
    if (tid < 192) {
      int lr = tid >> 6, j = (tid >> 2) & 15, cg = tid & 3;
      int i2 = irow + lr - 1;
      float acc8[8];
      float sum2 = 0.f;
      if (i2 >= 0 && i2 < 16) {
        #pragma unroll
        for (int c = 0; c < 8; ++c) acc8[c] = pb[cg * 8 + c];
        const float* xb = x + (size_t)b * 4096 * 64;
        const float* p00 = xb + ((size_t)(4 * i2 + 1) * 64 + (4 * j + 1)) * 64;
        for (int kq = 0; kq < 16; ++kq) {
          float4 a = ((const float4*)p00)[kq];
          float4 bq = ((const float4*)(p00 + 64))[kq];
          float4 cq = ((const float4*)(p00 + 4096))[kq];
          float4 dq = ((const float4*)(p00 + 4160))[kq];
          float xv[4] = {0.25f * (a.x + bq.x + cq.x + dq.x), 0.25f * (a.y + bq.y + cq.y + dq.y),
                         0.25f * (a.z + bq.z + cq.z + dq.z), 0.25f * (a.w + bq.w + cq.w + dq.w)};
          #pragma unroll
          for (int e = 0; e < 4; ++e) {
            const float* pwr = pw + (kq * 4 + e) * 32 + cg * 8;
            #pragma unroll
            for (int c = 0; c < 8; ++c) acc8[c] += xv[e] * pwr[c];
          }
        }
        #pragma unroll
        for (int c = 0; c < 8; ++c) {
          float v = acc8[c];
          v = v >= 0.f ? v : pa[cg * 8 + c] * v;
          ph_s[(lr * 16 + j) * 33 + cg * 8 + c] = v;
          sum2 += v * v;
        }
      } else {
        #pragma unroll
        for (int c = 0; c < 8; ++c) ph_s[(lr * 16 + j) * 33 + cg * 8 + c] = 0.f;
      }
      ssp[tid] = sum2;
    }
    __syncthreads();
    if (tid < 48) ss2[tid] = ssp[tid*4] + ssp[tid*4+1] + ssp[tid*4+2] + ssp[tid*4+3];
    __syncthreads();
    // write: thread = j*16 + u, u<9 = shift s
    int j = tid >> 4, u = tid & 15;
    if (u < 9) {
      float nn = 0.f;
      #pragma unroll
      for (int lr = 0; lr < 3; ++lr) {
        int i2 = irow + lr - 1;
        if (i2 < 0 || i2 > 15) continue;
        #pragma unroll
        for (int dj = 0; dj < 3; ++dj) {
          int pj = j + dj - 1;
          if (pj >= 0 && pj < 16) nn += ss2[lr * 16 + pj];
        }
      }
      float scale = 1.f / fmaxf(sqrtf(nn), 1e-6f);
      int lr = u / 3, dj = u % 3;
      int i2 = irow + lr - 1, pj = j + dj - 1;
      bool ok = (i2 >= 0 && i2 < 16 && pj >= 0 && pj < 16);
      size_t base = ((size_t)(b * 256 + irow * 16 + j)) * 288 + u * 32;
      #pragma unroll
      for (int q8 = 0; q8 < 4; ++q8) {
        short8 hv, lv;
        #pragma unroll
        for (int c = 0; c < 8; ++c) {
          float v = ok ? ph_s[(lr * 16 + pj) * 33 + q8 * 8 + c] * scale : 0.f;
          short hi = f2bf(v);
          hv[c] = hi;
          lv[c] = f2bf(v - bf2f(hi));
        }
        *(short8*)(Bh + base + q8 * 8) = hv;
        *(short8*)(Bl + base + q8 * 8) = lv;
      }
    }
  }
}

// ---------------- standalone K4a (fallback path only): gather g (bf16) -> Bbf ----------------
__global__ __launch_bounds__(256) void k_bgather(const short* __restrict__ g,
                                                 short* __restrict__ Bbf) {
  int r = blockIdx.x;              // 0..15 = (ry,rx)
  int bl = blockIdx.y;
  int ry = r >> 2, rx = r & 3;
  int t = threadIdx.x;
  int wv = t >> 6, l = t & 63;
  int jj = t >> 4, c4 = (t & 15) * 4;
  __shared__ short tile[256 * 66];
  const short* gb = g + (size_t)bl * 4096 * 64;
  for (int s = 0; s < 9; ++s) {
    int dy = s / 3, dx = s % 3;
    {
      int col = 4 * jj + rx + 4 * dx - 4;
      #pragma unroll
      for (int i2 = 0; i2 < 16; ++i2) {
        int row = 4 * i2 + ry + 4 * dy - 4;
        short4 v = make_short4(0, 0, 0, 0);
        if (row >= 0 && row < 64 && col >= 0 && col < 64)
          v = *(const short4*)(gb + (((size_t)row << 6) + col) * 64 + c4);
        int ij = i2 * 16 + jj;
        tile[ij * 66 + c4 + 0] = v.x;
        tile[ij * 66 + c4 + 1] = v.y;
        tile[ij * 66 + c4 + 2] = v.z;
        tile[ij * 66 + c4 + 3] = v.w;
      }
    }
    __syncthreads();
    #pragma unroll
    for (int cc = 0; cc < 16; ++cc) {
      int c = cc * 4 + wv;
      int n = r * 64 + c;
      unsigned* dstrow = (unsigned*)(Bbf + ((size_t)bl * 1024 + n) * 2304 + s * 256);
      #pragma unroll
      for (int half = 0; half < 2; ++half) {
        int ij0 = half * 128 + 2 * l;
        unsigned v = (unsigned)(unsigned short)tile[ij0 * 66 + c]
                   | ((unsigned)(unsigned short)tile[(ij0 + 1) * 66 + c] << 16);
        dstrow[half * 64 + l] = v;
      }
    }
    __syncthreads();
  }
}

// ---------------- K_mid (fused): blocks x<16 = bgather; x>=16 = scores+softmax ----------------
__global__ __launch_bounds__(512) void k_mid(const short* __restrict__ g,
                                             short* __restrict__ Bbf,
                                             const short* __restrict__ thetaPh,
                                             const short* __restrict__ thetaPl,
                                             const short* __restrict__ Bh,
                                             const short* __restrict__ Bl,
                                             short* __restrict__ attnp,
                                             int doGather) {
  __shared__ __align__(16) short smem[32768];
  int tid = threadIdx.x;
  int b = blockIdx.y;
  if (blockIdx.x < 16) {
    // ======== gather path (256 active threads; 512-thread block for uniformity) ========
    if (!doGather) return;
    int r = blockIdx.x, bl = b;
    int ry = r >> 2, rx = r & 3;
    short* tile = smem;            // 256*66 shorts = 33 KB (fits in 64 KB pool)
    const short* gb = g + (size_t)bl * 4096 * 64;
    for (int s = 0; s < 9; ++s) {
      int dy = s / 3, dx = s % 3;
      if (tid < 256) {
        int jj = tid >> 4, c4 = (tid & 15) * 4;
        int col = 4 * jj + rx + 4 * dx - 4;
        #pragma unroll
        for (int i2 = 0; i2 < 16; ++i2) {
          int row = 4 * i2 + ry + 4 * dy - 4;
          short4 v = make_short4(0, 0, 0, 0);
          if (row >= 0 && row < 64 && col >= 0 && col < 64)
            v = *(const short4*)(gb + (((size_t)row << 6) + col) * 64 + c4);
          int ij = i2 * 16 + jj;
          tile[ij * 66 + c4 + 0] = v.x;
          tile[ij * 66 + c4 + 1] = v.y;
          tile[ij * 66 + c4 + 2] = v.z;
          tile[ij * 66 + c4 + 3] = v.w;
        }
      }
      __syncthreads();
      if (tid < 256) {
        int wv = tid >> 6, l = tid & 63;
        #pragma unroll
        for (int cc = 0; cc < 16; ++cc) {
          int c = cc * 4 + wv;
          int n = r * 64 + c;
          unsigned* dstrow = (unsigned*)(Bbf + ((size_t)bl * 1024 + n) * 2304 + s * 256);
          #pragma unroll
          for (int half = 0; half < 2; ++half) {
            int ij0 = half * 128 + 2 * l;
            unsigned v = (unsigned)(unsigned short)tile[ij0 * 66 + c]
                       | ((unsigned)(unsigned short)tile[(ij0 + 1) * 66 + c] << 16);
            dstrow[half * 64 + l] = v;
          }
        }
      }
      __syncthreads();
    }
    return;
  }
  // ======== scores + softmax path ========
  int mt = blockIdx.x - 16;        // 0..31
  // zero attnp ring: 8320 short8-chunks per batch
  {
    int c = mt + 32 * tid;
    if (c < 8320) {
      int p = c >> 5, off = (c & 31) * 8;
      int r, cc; ring_px(p, r, cc);
      *(short8*)(attnp + ((size_t)(b * 66 + r) * 66 + cc) * 256 + off) = (short8)0;
    }
  }
  int w = tid >> 6, lane = tid & 63;
  int wm = w >> 2, wn = w & 3;
  int quad = lane >> 4, l16 = lane & 15;

  short* Ash = smem;               // 4096 shorts (128x32)
  short* Asl = smem + 4096;        // 4096
  short* Bsh = smem + 8192;        // 8192 shorts (256x32)
  short* Bsl = smem + 16384;       // 8192
  float* wred = (float*)(smem + 24576);  // 512 floats

  f32x4 acc[4][4];
  #pragma unroll
  for (int i = 0; i < 4; ++i)
    #pragma unroll
    for (int j = 0; j < 4; ++j) acc[i][j] = (f32x4)0.f;

  int ar = w * 16 + (lane >> 2);
  int am = mt * 128 + ar;
  int aQy = am >> 6, aQx = am & 63;
  int achunk = (lane & 3) * 8;

  for (int s = 0; s < 9; ++s) {
    int di = s / 3, dj = s % 3;
    __syncthreads();
    size_t aoff = ((size_t)(b * 66 + aQy + di) * 66 + (aQx + dj)) * 32 + achunk;
    gload_lds16(thetaPh + aoff, Ash + w * 512 + lane * 8);
    gload_lds16(thetaPl + aoff, Asl + w * 512 + lane * 8);
    #pragma unroll
    for (int p = 0; p < 2; ++p) {
      int nl = w * 32 + p * 16 + (lane >> 2);
      size_t boff = ((size_t)(b * 256 + nl)) * 288 + s * 32 + achunk;
      gload_lds16(Bh + boff, Bsh + w * 1024 + p * 512 + lane * 8);
      gload_lds16(Bl + boff, Bsl + w * 1024 + p * 512 + lane * 8);
    }
    __syncthreads();
    #pragma unroll
    for (int pass = 0; pass < 3; ++pass) {
      const short* Asrc = (pass < 2) ? Ash : Asl;
      const short* Bsrc = (pass == 1) ? Bsl : Bsh;
      short8 af[4], bfr[4];
      #pragma unroll
      for (int i = 0; i < 4; ++i)
        af[i] = *(const short8*)(Asrc + (wm * 64 + i * 16 + l16) * 32 + quad * 8);
      #pragma unroll
      for (int j = 0; j < 4; ++j)
        bfr[j] = *(const short8*)(Bsrc + (wn * 64 + j * 16 + l16) * 32 + quad * 8);
      #pragma unroll
      for (int i = 0; i < 4; ++i)
        #pragma unroll
        for (int j = 0; j < 4; ++j)
          acc[i][j] = __builtin_amdgcn_mfma_f32_16x16x32_bf16(af[i], bfr[j], acc[i][j], 0, 0, 0);
    }
  }

  float rmax[4][4];
  #pragma unroll
  for (int i = 0; i < 4; ++i)
    #pragma unroll
    for (int reg = 0; reg < 4; ++reg) {
      float m = -1e30f;
      #pragma unroll
      for (int j = 0; j < 4; ++j) m = fmaxf(m, acc[i][j][reg]);
      #pragma unroll
      for (int off = 1; off < 16; off <<= 1) m = fmaxf(m, __shfl_xor(m, off));
      rmax[i][reg] = m;
    }
  if (l16 == 0) {
    #pragma unroll
    for (int i = 0; i < 4; ++i)
      #pragma unroll
      for (int reg = 0; reg < 4; ++reg)
        wred[(wm * 64 + i * 16 + quad * 4 + reg) * 4 + wn] = rmax[i][reg];
  }
  __syncthreads();
  #pragma unroll
  for (int i = 0; i < 4; ++i)
    #pragma unroll
    for (int reg = 0; reg < 4; ++reg) {
      int r = wm * 64 + i * 16 + quad * 4 + reg;
      rmax[i][reg] = fmaxf(fmaxf(wred[r * 4 + 0], wred[r * 4 + 1]),
                           fmaxf(wred[r * 4 + 2], wred[r * 4 + 3]));
    }
  __syncthreads();
  float rsum[4][4];
  #pragma unroll
  for (int i = 0; i < 4; ++i)
    #pragma unroll
    for (int reg = 0; reg < 4; ++reg) {
      float s = 0.f;
      #pragma unroll
      for (int j = 0; j < 4; ++j) {
        float e = expf((acc[i][j][reg] - rmax[i][reg]) * 10.f);
        acc[i][j][reg] = e;
        s += e;
      }
      #pragma unroll
      for (int off = 1; off < 16; off <<= 1) s += __shfl_xor(s, off);
      rsum[i][reg] = s;
    }
  if (l16 == 0) {
    #pragma unroll
    for (int i = 0; i < 4; ++i)
      #pragma unroll
      for (int reg = 0; reg < 4; ++reg)
        wred[(wm * 64 + i * 16 + quad * 4 + reg) * 4 + wn] = rsum[i][reg];
  }
  __syncthreads();
  #pragma unroll
  for (int i = 0; i < 4; ++i)
    #pragma unroll
    for (int reg = 0; reg < 4; ++reg) {
      int r = wm * 64 + i * 16 + quad * 4 + reg;
      float tot = wred[r * 4 + 0] + wred[r * 4 + 1] + wred[r * 4 + 2] + wred[r * 4 + 3];
      rsum[i][reg] = 1.f / tot;
    }
  __syncthreads();
  #pragma unroll
  for (int i = 0; i < 4; ++i)
    #pragma unroll
    for (int reg = 0; reg < 4; ++reg) {
      int r = wm * 64 + i * 16 + quad * 4 + reg;
      #pragma unroll
      for (int j = 0; j < 4; ++j)
        smem[r * 256 + wn * 64 + j * 16 + l16] = f2bf(acc[i][j][reg] * rsum[i][reg]);
    }
  __syncthreads();
  {
    int r2 = tid >> 2, c2 = (tid & 3) * 64;
    int m2 = mt * 128 + r2;
    int Qy = m2 >> 6, Qx = m2 & 63;
    short8* dst = (short8*)(attnp + ((size_t)(b * 66 + Qy + 1) * 66 + (Qx + 1)) * 256 + c2);
    #pragma unroll
    for (int q = 0; q < 8; ++q) dst[q] = *(const short8*)(smem + r2 * 256 + c2 + q * 8);
  }
}

// ---------------- K4b: deconv GEMM — R6 version (best measured: 184.5us, 0 conflicts) ---------
// 2-barrier BK=64 schedule + conflict-free chunk swizzle + hoisted base pointers.
// R4/R5/R7/R8 established every schedule deviation (dbuf64, BK32-2ph, BK96, vmcnt-ring)
// regresses; this is the 2-phase family optimum. Launched split by half-batch (z=4 twice)
// purely for top-5 visibility of k_pre/k_mid (tiles disjoint -> bit-identical output).
__global__ __launch_bounds__(256) void k_gemm(const short* __restrict__ attnp,
                                              const short* __restrict__ Bbf,
                                              float* __restrict__ out,
                                              int b0) {
  int lid = blockIdx.x + 32 * blockIdx.y + 256 * blockIdx.z;
  int nwg = 256 * gridDim.z;
  int chunk = nwg >> 3;
  int swz = (lid & 7) * chunk + (lid >> 3);
  int mt = swz & 31;               // 0..31
  int nt = (swz >> 5) & 7;         // 0..7
  int bl = swz >> 8;
  int b = b0 + bl;
  int tid = threadIdx.x;
  int wave = tid >> 6, lane = tid & 63;
  int wm = wave >> 1, wn = wave & 1;
  int quad = lane >> 4, l16 = lane & 15;

  __shared__ __align__(16) short As[8192];   // 2 u-chunks x 128x32, swizzled
  __shared__ __align__(16) short Bs[8192];

  f32x4 acc[4][4];
  #pragma unroll
  for (int i = 0; i < 4; ++i)
    #pragma unroll
    for (int j = 0; j < 4; ++j) acc[i][j] = (f32x4)0.f;

  const short* Ab = attnp + (size_t)b * 66 * 66 * 256;
  const short* Bb = Bbf + (size_t)bl * 1024 * 2304 + (size_t)(nt * 128) * 2304;

  // Staging map: row = wave*32 + t*16 + (lane>>2), phys chunk = lane&3.
  // Swizzle: logical chunk = phys ^ ((row>>1)&3) = (lane&3) ^ ((lane>>3)&3).
  int larow = lane >> 2;
  int cl8 = ((lane & 3) ^ ((lane >> 3) & 3)) * 8;   // logical col offset (shorts)

  // Hoisted per-thread base pointers (t=0,1). Per-iter offsets are wave-uniform.
  int rr0 = wave * 32 + larow, rr1 = rr0 + 16;
  int m0 = mt * 128 + rr0,     m1 = mt * 128 + rr1;
  const short* aB0 = Ab + ((size_t)(((m0 >> 6) + 2) * 66 + (m0 & 63) + 2) << 8) + cl8;
  const short* aB1 = Ab + ((size_t)(((m1 >> 6) + 2) * 66 + (m1 & 63) + 2) << 8) + cl8;
  const short* bB0 = Bb + (size_t)rr0 * 2304 + cl8;
  const short* bB1 = Bb + (size_t)rr1 * 2304 + cl8;

  int po = (quad ^ ((l16 >> 1) & 3)) * 8;   // read-side physical chunk offset (shorts)

  for (int kb0 = 0; kb0 < 36; ++kb0) {
    __syncthreads();
    #pragma unroll
    for (int u = 0; u < 2; ++u) {
      int kb = kb0 * 2 + u;
      int s = kb >> 3;
      int dy = (s * 11) >> 5;            // s/3 for s in 0..8
      int dx = s - 3 * dy;
      int offA = (kb & 7) * 32 - ((dy * 66 + dx) << 8);   // wave-uniform
      int offB = kb * 32;                                  // wave-uniform
      gload_lds16(aB0 + offA, As + u * 4096 + wave * 1024 + lane * 8);
      gload_lds16(bB0 + offB, Bs + u * 4096 + wave * 1024 + lane * 8);
      gload_lds16(aB1 + offA, As + u * 4096 + wave * 1024 + 512 + lane * 8);
      gload_lds16(bB1 + offB, Bs + u * 4096 + wave * 1024 + 512 + lane * 8);
    }
    __syncthreads();
    #pragma unroll
    for (int u = 0; u < 2; ++u) {
      short8 af[4], bfr[4];
      #pragma unroll
      for (int i = 0; i < 4; ++i)
        af[i] = *(const short8*)(As + u * 4096 + (wm * 64 + i * 16 + l16) * 32 + po);
      #pragma unroll
      for (int j = 0; j < 4; ++j)
        bfr[j] = *(const short8*)(Bs + u * 4096 + (wn * 64 + j * 16 + l16) * 32 + po);
      #pragma unroll
      for (int i = 0; i < 4; ++i)
        #pragma unroll
        for (int j = 0; j < 4; ++j)
          acc[i][j] = __builtin_amdgcn_mfma_f32_16x16x32_bf16(af[i], bfr[j], acc[i][j], 0, 0, 0);
    }
  }

  const float inv6 = 1.f / 6.f;
  #pragma unroll
  for (int i = 0; i < 4; ++i) {
    int mbase = mt * 128 + wm * 64 + i * 16 + quad * 4;
    #pragma unroll
    for (int j = 0; j < 4; ++j) {
      int n = nt * 128 + wn * 64 + j * 16 + l16;
      int r = n >> 6; int c = n & 63;
      int ry = r >> 2, rx = r & 3;
      #pragma unroll
      for (int reg = 0; reg < 4; ++reg) {
        int m = mbase + reg;
        int Qy = m >> 6, Qx = m & 63;
        out[(((size_t)b * 256 + 4 * Qy + ry) * 256 + (4 * Qx + rx)) * 64 + c]
            = acc[i][j][reg] * inv6;
      }
    }
  }
}

extern "C" void kernel_launch(void* const* d_in, const int* in_sizes, int n_in,
                              void* d_out, int out_size, void* d_ws, size_t ws_size,
                              hipStream_t stream) {
  const float* x           = (const float*)d_in[0];
  const float* theta_w     = (const float*)d_in[1];
  const float* theta_b     = (const float*)d_in[2];
  const float* theta_alpha = (const float*)d_in[3];
  const float* phi_w       = (const float*)d_in[4];
  const float* phi_b       = (const float*)d_in[5];
  const float* phi_alpha   = (const float*)d_in[6];
  const float* g_w         = (const float*)d_in[7];
  const float* g_b         = (const float*)d_in[8];
  const float* g_alpha     = (const float*)d_in[9];
  float* out = (float*)d_out;

  char* w = (char*)d_ws;
  size_t off = 0;
  auto alloc = [&](size_t bytes) { void* p = w + off; off += (bytes + 255) & ~255ull; return p; };
  short* g       = (short*)alloc(8ull * 4096 * 64 * 2);       // 4 MB (bf16)
  size_t thp_bytes = 8ull * 66 * 66 * 32 * 2;                 // 2.23 MB
  short* thetaPh = (short*)alloc(thp_bytes);
  short* thetaPl = (short*)alloc(thp_bytes);
  short* Bh      = (short*)alloc(8ull * 256 * 288 * 2);       // 1.18 MB
  short* Bl      = (short*)alloc(8ull * 256 * 288 * 2);
  size_t attnp_bytes = 8ull * 66 * 66 * 256 * 2;              // 17.8 MB
  short* attnp   = (short*)alloc(attnp_bytes);
  size_t bbf_full = 8ull * 1024 * 2304 * 2;                   // 37.7 MB
  bool full = (off + bbf_full) <= ws_size;
  short* Bbf = (short*)alloc(full ? bbf_full : bbf_full / 8);

  hipLaunchKernelGGL(k_pre, dim3(256 + 128), dim3(256), 0, stream,
                     x, theta_w, theta_b, theta_alpha, phi_w, phi_b, phi_alpha,
                     g_w, g_b, g_alpha, thetaPh, thetaPl, g, Bh, Bl);
  if (full) {
    hipLaunchKernelGGL(k_mid, dim3(48, BB), dim3(512), 0, stream,
                       g, Bbf, thetaPh, thetaPl, Bh, Bl, attnp, 1);
    // Split k_gemm into two half-batch launches (diagnostic: lowers top-5 cutoff to ~92us
    // so k_pre/k_mid surface if they are the hidden ~190us). Tiles disjoint -> identical.
    hipLaunchKernelGGL(k_gemm, dim3(32, 8, 4), dim3(256), 0, stream, attnp, Bbf, out, 0);
    hipLaunchKernelGGL(k_gemm, dim3(32, 8, 4), dim3(256), 0, stream,
                       attnp, Bbf + 4ull * 1024 * 2304, out, 4);
  } else {
    hipLaunchKernelGGL(k_mid, dim3(48, BB), dim3(512), 0, stream,
                       g, Bbf, thetaPh, thetaPl, Bh, Bl, attnp, 0);
    for (int b = 0; b < BB; ++b) {
      hipLaunchKernelGGL(k_bgather, dim3(16, 1), dim3(256), 0, stream,
                         g + (size_t)b * 4096 * 64, Bbf);
      hipLaunchKernelGGL(k_gemm, dim3(32, 8, 1), dim3(256), 0, stream, attnp, Bbf, out, b);
    }
  }
}

// Round 15
// 377.927 us; speedup vs baseline: 1.1135x; 1.1135x over previous
//
#include <hip/hip_runtime.h>
#include <math.h>

// Problem constants: B=8, H=W=64, C=64, CI=32, SCALE=4, PATCH=3, N=256
#define BB 8

typedef __attribute__((ext_vector_type(8))) short short8;   // 8 x bf16 bits
typedef __attribute__((ext_vector_type(4))) float f32x4;

__device__ inline short f2bf(float x) {          // fp32 -> bf16 (RNE)
  unsigned u = __builtin_bit_cast(unsigned, x);
  u += 0x7fffu + ((u >> 16) & 1u);
  return (short)(u >> 16);
}
__device__ inline float bf2f(short h) {
  unsigned u = ((unsigned)(unsigned short)h) << 16;
  return __builtin_bit_cast(float, u);
}

__device__ inline void gload_lds16(const void* g, void* l) {
  __builtin_amdgcn_global_load_lds(
      (const __attribute__((address_space(1))) void*)g,
      (__attribute__((address_space(3))) void*)l, 16, 0, 0);
}

// Map ring-pixel index p (0..259) of a 66x66 frame to (row, col).
__device__ inline void ring_px(int p, int& r, int& cc) {
  if (p < 66) { r = 0; cc = p; }
  else if (p < 132) { r = 65; cc = p - 66; }
  else { int q = p - 132; r = 1 + (q >> 1); cc = (q & 1) ? 65 : 0; }
}

// ---------------- K1 (fused): blocks 0..255 = theta&g conv; 256..383 = phi+phin ----------------
__global__ __launch_bounds__(256) void k_pre(const float* __restrict__ x,
                          const float* __restrict__ theta_w, const float* __restrict__ theta_b,
                          const float* __restrict__ theta_alpha,
                          const float* __restrict__ phi_w, const float* __restrict__ phi_b,
                          const float* __restrict__ phi_alpha,
                          const float* __restrict__ g_w, const float* __restrict__ g_b,
                          const float* __restrict__ g_alpha,
                          short* __restrict__ thetaPh, short* __restrict__ thetaPl,
                          short* __restrict__ gOut,
                          short* __restrict__ Bh, short* __restrict__ Bl) {
  __shared__ __align__(16) float spool[14528];
  int tid = threadIdx.x;
  if (blockIdx.x < 256) {
    // ======== theta & g path ========
    int bid = blockIdx.x;
    int b = bid >> 5, pg = bid & 31;
    int px0 = pg * 128;
    // zero thetaP ring: 1040 short8-chunks per array per batch
    if (tid <= 32) {
      int c = pg + 32 * tid;
      if (c < 1040) {
        int p = c >> 2, off = (c & 3) * 8;
        int r, cc; ring_px(p, r, cc);
        size_t ad = ((size_t)(b * 66 + r) * 66 + cc) * 32 + off;
        short8 z = (short8)0;
        *(short8*)(thetaPh + ad) = z;
        *(short8*)(thetaPl + ad) = z;
      }
    }
    float* gw = spool;              // 64*64
    float* tw = spool + 4096;       // 64*32
    float* xs = spool + 6144;       // 64*128
    float* gb_s = spool + 14336; float* ga_s = spool + 14400;
    float* tb_s = spool + 14464; float* ta_s = spool + 14496;
    for (int idx = tid; idx < 1024; idx += 256) ((float4*)gw)[idx] = ((const float4*)g_w)[idx];
    for (int idx = tid; idx < 512; idx += 256)  ((float4*)tw)[idx] = ((const float4*)theta_w)[idx];
    if (tid < 64) { gb_s[tid] = g_b[tid]; ga_s[tid] = g_alpha[tid]; }
    else if (tid < 96) { tb_s[tid - 64] = theta_b[tid - 64]; ta_s[tid - 64] = theta_alpha[tid - 64]; }
    {
      int p = tid >> 1, half = tid & 1;
      const float* xp = x + ((size_t)b * 4096 + px0 + p) * 64 + half * 32;
      #pragma unroll
      for (int i = 0; i < 8; ++i) {
        float4 v = ((const float4*)xp)[i];
        int k = half * 32 + i * 4;
        xs[(k + 0) * 128 + p] = v.x; xs[(k + 1) * 128 + p] = v.y;
        xs[(k + 2) * 128 + p] = v.z; xs[(k + 3) * 128 + p] = v.w;
      }
    }
    __syncthreads();
    int pp = tid >> 2, q = tid & 3;
    float accg[2][16], acct[2][8];
    #pragma unroll
    for (int c = 0; c < 16; ++c) { float bv = gb_s[q * 16 + c]; accg[0][c] = bv; accg[1][c] = bv; }
    #pragma unroll
    for (int c = 0; c < 8; ++c)  { float bv = tb_s[q * 8 + c];  acct[0][c] = bv; acct[1][c] = bv; }
    for (int k = 0; k < 64; ++k) {
      float x0 = xs[k * 128 + 2 * pp], x1 = xs[k * 128 + 2 * pp + 1];
      const float* gwr = gw + k * 64 + q * 16;
      const float* twr = tw + k * 32 + q * 8;
      #pragma unroll
      for (int c = 0; c < 16; ++c) { float wv = gwr[c]; accg[0][c] += x0 * wv; accg[1][c] += x1 * wv; }
      #pragma unroll
      for (int c = 0; c < 8; ++c)  { float wv = twr[c]; acct[0][c] += x0 * wv; acct[1][c] += x1 * wv; }
    }
    #pragma unroll
    for (int e = 0; e < 2; ++e) {
      int px = px0 + 2 * pp + e;
      // g output bf16 (consumed only by gather, which converted anyway)
      short* gp = gOut + ((size_t)(b * 4096 + px)) * 64 + q * 16;
      short8 gv0, gv1;
      #pragma unroll
      for (int c = 0; c < 16; ++c) {
        float v = accg[e][c];
        float a = ga_s[q * 16 + c];
        v = v >= 0.f ? v : a * v;
        short hb = f2bf(v);
        if (c < 8) gv0[c] = hb; else gv1[c - 8] = hb;
      }
      *(short8*)(gp) = gv0;
      *(short8*)(gp + 8) = gv1;
      int h = px >> 6, w = px & 63;
      size_t off = ((size_t)(b * 66 + h + 1) * 66 + (w + 1)) * 32 + q * 8;
      short8 hv, lv;
      #pragma unroll
      for (int c = 0; c < 8; ++c) {
        float t = acct[e][c];
        float a = ta_s[q * 8 + c];
        float v = t >= 0.f ? t : a * t;
        short hi = f2bf(v);
        hv[c] = hi;
        lv[c] = f2bf(v - bf2f(hi));
      }
      *(short8*)(thetaPh + off) = hv;
      *(short8*)(thetaPl + off) = lv;
    }
  } else {
    // ======== phi + phin path: one block per (b, i-row), halo recomputed ========
    int bid = blockIdx.x - 256;
    int b = bid >> 4, irow = bid & 15;
    float* pw   = spool;            // 64*32
    float* pb   = spool + 2048;     // 32
    float* pa   = spool + 2080;     // 32
    float* ph_s = spool + 2112;     // 48*33
    float* ss2  = spool + 3696;     // 48
    float* ssp  = spool + 3744;     // 192
    for (int idx = tid; idx < 512; idx += 256) ((float4*)pw)[idx] = ((const float4*)phi_w)[idx];
    if (tid < 32) { pb[tid] = phi_b[tid]; pa[tid] = phi_alpha[tid]; }
    __syncthreads();
    // conv: threads t = lr*64 + j*4 + cg  (lr<3, j<16, cg<4 -> 8 channels each)
    if (tid < 192) {
      int lr = tid >> 6, j = (tid >> 2) & 15, cg = tid & 3;
      int i2 = irow + lr - 1;
      float acc8[8];
      float sum2 = 0.f;
      if (i2 >= 0 && i2 < 16) {
        #pragma unroll
        for (int c = 0; c < 8; ++c) acc8[c] = pb[cg * 8 + c];
        const float* xb = x + (size_t)b * 4096 * 64;
        const float* p00 = xb + ((size_t)(4 * i2 + 1) * 64 + (4 * j + 1)) * 64;
        for (int kq = 0; kq < 16; ++kq) {
          float4 a = ((const float4*)p00)[kq];
          float4 bq = ((const float4*)(p00 + 64))[kq];
          float4 cq = ((const float4*)(p00 + 4096))[kq];
          float4 dq = ((const float4*)(p00 + 4160))[kq];
          float xv[4] = {0.25f * (a.x + bq.x + cq.x + dq.x), 0.25f * (a.y + bq.y + cq.y + dq.y),
                         0.25f * (a.z + bq.z + cq.z + dq.z), 0.25f * (a.w + bq.w + cq.w + dq.w)};
          #pragma unroll
          for (int e = 0; e < 4; ++e) {
            const float* pwr = pw + (kq * 4 + e) * 32 + cg * 8;
            #pragma unroll
            for (int c = 0; c < 8; ++c) acc8[c] += xv[e] * pwr[c];
          }
        }
        #pragma unroll
        for (int c = 0; c < 8; ++c) {
          float v = acc8[c];
          v = v >= 0.f ? v : pa[cg * 8 + c] * v;
          ph_s[(lr * 16 + j) * 33 + cg * 8 + c] = v;
          sum2 += v * v;
        }
      } else {
        #pragma unroll
        for (int c = 0; c < 8; ++c) ph_s[(lr * 16 + j) * 33 + cg * 8 + c] = 0.f;
      }
      ssp[tid] = sum2;
    }
    __syncthreads();
    if (tid < 48) ss2[tid] = ssp[tid*4] + ssp[tid*4+1] + ssp[tid*4+2] + ssp[tid*4+3];
    __syncthreads();
    // write: thread = j*16 + u, u<9 = shift s
    int j = tid >> 4, u = tid & 15;
    if (u < 9) {
      float nn = 0.f;
      #pragma unroll
      for (int lr = 0; lr < 3; ++lr) {
        int i2 = irow + lr - 1;
        if (i2 < 0 || i2 > 15) continue;
        #pragma unroll
        for (int dj = 0; dj < 3; ++dj) {
          int pj = j + dj - 1;
          if (pj >= 0 && pj < 16) nn += ss2[lr * 16 + pj];
        }
      }
      float scale = 1.f / fmaxf(sqrtf(nn), 1e-6f);
      int lr = u / 3, dj = u % 3;
      int i2 = irow + lr - 1, pj = j + dj - 1;
      bool ok = (i2 >= 0 && i2 < 16 && pj >= 0 && pj < 16);
      size_t base = ((size_t)(b * 256 + irow * 16 + j)) * 288 + u * 32;
      #pragma unroll
      for (int q8 = 0; q8 < 4; ++q8) {
        short8 hv, lv;
        #pragma unroll
        for (int c = 0; c < 8; ++c) {
          float v = ok ? ph_s[(lr * 16 + pj) * 33 + q8 * 8 + c] * scale : 0.f;
          short hi = f2bf(v);
          hv[c] = hi;
          lv[c] = f2bf(v - bf2f(hi));
        }
        *(short8*)(Bh + base + q8 * 8) = hv;
        *(short8*)(Bl + base + q8 * 8) = lv;
      }
    }
  }
}

// ---------------- standalone K4a (fallback path only): gather g (bf16) -> Bbf ----------------
__global__ __launch_bounds__(256) void k_bgather(const short* __restrict__ g,
                                                 short* __restrict__ Bbf) {
  int r = blockIdx.x;              // 0..15 = (ry,rx)
  int bl = blockIdx.y;
  int ry = r >> 2, rx = r & 3;
  int t = threadIdx.x;
  int wv = t >> 6, l = t & 63;
  int jj = t >> 4, c4 = (t & 15) * 4;
  __shared__ short tile[256 * 66];
  const short* gb = g + (size_t)bl * 4096 * 64;
  for (int s = 0; s < 9; ++s) {
    int dy = s / 3, dx = s % 3;
    {
      int col = 4 * jj + rx + 4 * dx - 4;
      #pragma unroll
      for (int i2 = 0; i2 < 16; ++i2) {
        int row = 4 * i2 + ry + 4 * dy - 4;
        short4 v = make_short4(0, 0, 0, 0);
        if (row >= 0 && row < 64 && col >= 0 && col < 64)
          v = *(const short4*)(gb + (((size_t)row << 6) + col) * 64 + c4);
        int ij = i2 * 16 + jj;
        tile[ij * 66 + c4 + 0] = v.x;
        tile[ij * 66 + c4 + 1] = v.y;
        tile[ij * 66 + c4 + 2] = v.z;
        tile[ij * 66 + c4 + 3] = v.w;
      }
    }
    __syncthreads();
    #pragma unroll
    for (int cc = 0; cc < 16; ++cc) {
      int c = cc * 4 + wv;
      int n = r * 64 + c;
      unsigned* dstrow = (unsigned*)(Bbf + ((size_t)bl * 1024 + n) * 2304 + s * 256);
      #pragma unroll
      for (int half = 0; half < 2; ++half) {
        int ij0 = half * 128 + 2 * l;
        unsigned v = (unsigned)(unsigned short)tile[ij0 * 66 + c]
                   | ((unsigned)(unsigned short)tile[(ij0 + 1) * 66 + c] << 16);
        dstrow[half * 64 + l] = v;
      }
    }
    __syncthreads();
  }
}

// ---------------- K_mid (fused): blocks x<16 = bgather; x>=16 = scores+softmax ----------------
// Score path v2: (1) Ph window (4x66 pixels x 32ch = union of all 9 shifts for this block's
// 128 A-rows) staged ONCE -- removes 2 of 6 gloads per round and all Ph re-staging;
// (2) Bsh/Bsl get the R6-proven chunk-XOR swizzle (phys = logical ^ ((row>>1)&3)) applied
// on the global source + inverted on the fragment read -- removes the 8-way bank conflicts
// on B ds_read_b128 (identical index algebra to k_gemm's verified-0-conflict fix).
__global__ __launch_bounds__(512) void k_mid(const short* __restrict__ g,
                                             short* __restrict__ Bbf,
                                             const short* __restrict__ thetaPh,
                                             const short* __restrict__ thetaPl,
                                             const short* __restrict__ Bh,
                                             const short* __restrict__ Bl,
                                             short* __restrict__ attnp,
                                             int doGather) {
  __shared__ __align__(16) short smem[32768];
  int tid = threadIdx.x;
  int b = blockIdx.y;
  if (blockIdx.x < 16) {
    // ======== gather path (256 active threads; 512-thread block for uniformity) ========
    if (!doGather) return;
    int r = blockIdx.x, bl = b;
    int ry = r >> 2, rx = r & 3;
    short* tile = smem;            // 256*66 shorts = 33 KB
    const short* gb = g + (size_t)bl * 4096 * 64;
    for (int s = 0; s < 9; ++s) {
      int dy = s / 3, dx = s % 3;
      if (tid < 256) {
        int jj = tid >> 4, c4 = (tid & 15) * 4;
        int col = 4 * jj + rx + 4 * dx - 4;
        #pragma unroll
        for (int i2 = 0; i2 < 16; ++i2) {
          int row = 4 * i2 + ry + 4 * dy - 4;
          short4 v = make_short4(0, 0, 0, 0);
          if (row >= 0 && row < 64 && col >= 0 && col < 64)
            v = *(const short4*)(gb + (((size_t)row << 6) + col) * 64 + c4);
          int ij = i2 * 16 + jj;
          tile[ij * 66 + c4 + 0] = v.x;
          tile[ij * 66 + c4 + 1] = v.y;
          tile[ij * 66 + c4 + 2] = v.z;
          tile[ij * 66 + c4 + 3] = v.w;
        }
      }
      __syncthreads();
      if (tid < 256) {
        int wv = tid >> 6, l = tid & 63;
        #pragma unroll
        for (int cc = 0; cc < 16; ++cc) {
          int c = cc * 4 + wv;
          int n = r * 64 + c;
          unsigned* dstrow = (unsigned*)(Bbf + ((size_t)bl * 1024 + n) * 2304 + s * 256);
          #pragma unroll
          for (int half = 0; half < 2; ++half) {
            int ij0 = half * 128 + 2 * l;
            unsigned v = (unsigned)(unsigned short)tile[ij0 * 66 + c]
                       | ((unsigned)(unsigned short)tile[(ij0 + 1) * 66 + c] << 16);
            dstrow[half * 64 + l] = v;
          }
        }
      }
      __syncthreads();
    }
    return;
  }
  // ======== scores + softmax path ========
  int mt = blockIdx.x - 16;        // 0..31
  // zero attnp ring: 8320 short8-chunks per batch
  {
    int c = mt + 32 * tid;
    if (c < 8320) {
      int p = c >> 5, off = (c & 31) * 8;
      int r, cc; ring_px(p, r, cc);
      *(short8*)(attnp + ((size_t)(b * 66 + r) * 66 + cc) * 256 + off) = (short8)0;
    }
  }
  int w = tid >> 6, lane = tid & 63;
  int wm = w >> 2, wn = w & 3;
  int quad = lane >> 4, l16 = lane & 15;

  short* Wph = smem;                     // 8448 shorts: Ph window [4 rows][66 px][32 ch]
  short* Asl = smem + 8448;              // 4096: Pl tile (per round)
  short* Bsh = smem + 12544;             // 8192 (swizzled)
  short* Bsl = smem + 20736;             // 8192 (swizzled)
  float* wred = (float*)(smem + 28928);  // 512 floats

  f32x4 acc[4][4];
  #pragma unroll
  for (int i = 0; i < 4; ++i)
    #pragma unroll
    for (int j = 0; j < 4; ++j) acc[i][j] = (f32x4)0.f;

  int ar = w * 16 + (lane >> 2);
  int am = mt * 128 + ar;
  int aQy = am >> 6, aQx = am & 63;
  int achunk = (lane & 3) * 8;

  // Hoisted: stage the Ph window (pixel rows mt*2 .. mt*2+3, cols 0..65) once.
  // 4*66*32 = 8448 shorts = 1056 x 16B granules; contiguous in global (row-major).
  {
    const short* wh = thetaPh + (size_t)(b * 66 + mt * 2) * 66 * 32;
    gload_lds16(wh + (size_t)tid * 8, Wph + tid * 8);
    gload_lds16(wh + (size_t)(tid + 512) * 8, Wph + (tid + 512) * 8);
    if (tid < 32)
      gload_lds16(wh + (size_t)(tid + 1024) * 8, Wph + (tid + 1024) * 8);
  }
  int cl8b = ((lane & 3) ^ ((lane >> 3) & 3)) * 8;   // B staging: logical col (swizzled src)
  int pob  = (quad ^ ((l16 >> 1) & 3)) * 8;          // B read: physical chunk offset

  for (int s = 0; s < 9; ++s) {
    int di = s / 3, dj = s % 3;
    __syncthreads();
    // Pl tile for this shift (pass-2 A operand), unswizzled as before
    gload_lds16(thetaPl + ((size_t)(b * 66 + aQy + di) * 66 + (aQx + dj)) * 32 + achunk,
                Asl + w * 512 + lane * 8);
    #pragma unroll
    for (int p = 0; p < 2; ++p) {
      int nl = w * 32 + p * 16 + (lane >> 2);
      size_t boff = ((size_t)(b * 256 + nl)) * 288 + s * 32 + cl8b;
      gload_lds16(Bh + boff, Bsh + w * 1024 + p * 512 + lane * 8);
      gload_lds16(Bl + boff, Bsl + w * 1024 + p * 512 + lane * 8);
    }
    __syncthreads();
    #pragma unroll
    for (int pass = 0; pass < 3; ++pass) {
      const short* Bsrc = (pass == 1) ? Bsl : Bsh;
      short8 af[4], bfr[4];
      if (pass < 2) {
        #pragma unroll
        for (int i = 0; i < 4; ++i)
          af[i] = *(const short8*)(Wph + ((wm + di) * 66 + i * 16 + l16 + dj) * 32 + quad * 8);
      } else {
        #pragma unroll
        for (int i = 0; i < 4; ++i)
          af[i] = *(const short8*)(Asl + (wm * 64 + i * 16 + l16) * 32 + quad * 8);
      }
      #pragma unroll
      for (int j = 0; j < 4; ++j)
        bfr[j] = *(const short8*)(Bsrc + (wn * 64 + j * 16 + l16) * 32 + pob);
      #pragma unroll
      for (int i = 0; i < 4; ++i)
        #pragma unroll
        for (int j = 0; j < 4; ++j)
          acc[i][j] = __builtin_amdgcn_mfma_f32_16x16x32_bf16(af[i], bfr[j], acc[i][j], 0, 0, 0);
    }
  }

  float rmax[4][4];
  #pragma unroll
  for (int i = 0; i < 4; ++i)
    #pragma unroll
    for (int reg = 0; reg < 4; ++reg) {
      float m = -1e30f;
      #pragma unroll
      for (int j = 0; j < 4; ++j) m = fmaxf(m, acc[i][j][reg]);
      #pragma unroll
      for (int off = 1; off < 16; off <<= 1) m = fmaxf(m, __shfl_xor(m, off));
      rmax[i][reg] = m;
    }
  if (l16 == 0) {
    #pragma unroll
    for (int i = 0; i < 4; ++i)
      #pragma unroll
      for (int reg = 0; reg < 4; ++reg)
        wred[(wm * 64 + i * 16 + quad * 4 + reg) * 4 + wn] = rmax[i][reg];
  }
  __syncthreads();
  #pragma unroll
  for (int i = 0; i < 4; ++i)
    #pragma unroll
    for (int reg = 0; reg < 4; ++reg) {
      int r = wm * 64 + i * 16 + quad * 4 + reg;
      rmax[i][reg] = fmaxf(fmaxf(wred[r * 4 + 0], wred[r * 4 + 1]),
                           fmaxf(wred[r * 4 + 2], wred[r * 4 + 3]));
    }
  __syncthreads();
  float rsum[4][4];
  #pragma unroll
  for (int i = 0; i < 4; ++i)
    #pragma unroll
    for (int reg = 0; reg < 4; ++reg) {
      float s = 0.f;
      #pragma unroll
      for (int j = 0; j < 4; ++j) {
        float e = expf((acc[i][j][reg] - rmax[i][reg]) * 10.f);
        acc[i][j][reg] = e;
        s += e;
      }
      #pragma unroll
      for (int off = 1; off < 16; off <<= 1) s += __shfl_xor(s, off);
      rsum[i][reg] = s;
    }
  if (l16 == 0) {
    #pragma unroll
    for (int i = 0; i < 4; ++i)
      #pragma unroll
      for (int reg = 0; reg < 4; ++reg)
        wred[(wm * 64 + i * 16 + quad * 4 + reg) * 4 + wn] = rsum[i][reg];
  }
  __syncthreads();
  #pragma unroll
  for (int i = 0; i < 4; ++i)
    #pragma unroll
    for (int reg = 0; reg < 4; ++reg) {
      int r = wm * 64 + i * 16 + quad * 4 + reg;
      float tot = wred[r * 4 + 0] + wred[r * 4 + 1] + wred[r * 4 + 2] + wred[r * 4 + 3];
      rsum[i][reg] = 1.f / tot;
    }
  __syncthreads();
  #pragma unroll
  for (int i = 0; i < 4; ++i)
    #pragma unroll
    for (int reg = 0; reg < 4; ++reg) {
      int r = wm * 64 + i * 16 + quad * 4 + reg;
      #pragma unroll
      for (int j = 0; j < 4; ++j)
        smem[r * 256 + wn * 64 + j * 16 + l16] = f2bf(acc[i][j][reg] * rsum[i][reg]);
    }
  __syncthreads();
  {
    int r2 = tid >> 2, c2 = (tid & 3) * 64;
    int m2 = mt * 128 + r2;
    int Qy = m2 >> 6, Qx = m2 & 63;
    short8* dst = (short8*)(attnp + ((size_t)(b * 66 + Qy + 1) * 66 + (Qx + 1)) * 256 + c2);
    #pragma unroll
    for (int q = 0; q < 8; ++q) dst[q] = *(const short8*)(smem + r2 * 256 + c2 + q * 8);
  }
}

// ---------------- K4b: deconv GEMM — R6 version (best measured: 184.5us, 0 conflicts) ---------
// 2-barrier BK=64 schedule + conflict-free chunk swizzle + hoisted base pointers.
// All schedule deviations measured (dbuf64 R4, BK32-2ph R5, BK96 R7, vmcnt-ring R8, grid
// split R9) regress; this is the structure optimum. Single full-batch launch.
__global__ __launch_bounds__(256) void k_gemm(const short* __restrict__ attnp,
                                              const short* __restrict__ Bbf,
                                              float* __restrict__ out,
                                              int b0) {
  int lid = blockIdx.x + 32 * blockIdx.y + 256 * blockIdx.z;
  int nwg = 256 * gridDim.z;
  int chunk = nwg >> 3;
  int swz = (lid & 7) * chunk + (lid >> 3);
  int mt = swz & 31;               // 0..31
  int nt = (swz >> 5) & 7;         // 0..7
  int bl = swz >> 8;
  int b = b0 + bl;
  int tid = threadIdx.x;
  int wave = tid >> 6, lane = tid & 63;
  int wm = wave >> 1, wn = wave & 1;
  int quad = lane >> 4, l16 = lane & 15;

  __shared__ __align__(16) short As[8192];   // 2 u-chunks x 128x32, swizzled
  __shared__ __align__(16) short Bs[8192];

  f32x4 acc[4][4];
  #pragma unroll
  for (int i = 0; i < 4; ++i)
    #pragma unroll
    for (int j = 0; j < 4; ++j) acc[i][j] = (f32x4)0.f;

  const short* Ab = attnp + (size_t)b * 66 * 66 * 256;
  const short* Bb = Bbf + (size_t)bl * 1024 * 2304 + (size_t)(nt * 128) * 2304;

  // Staging map: row = wave*32 + t*16 + (lane>>2), phys chunk = lane&3.
  // Swizzle: logical chunk = phys ^ ((row>>1)&3) = (lane&3) ^ ((lane>>3)&3).
  int larow = lane >> 2;
  int cl8 = ((lane & 3) ^ ((lane >> 3) & 3)) * 8;   // logical col offset (shorts)

  // Hoisted per-thread base pointers (t=0,1). Per-iter offsets are wave-uniform.
  int rr0 = wave * 32 + larow, rr1 = rr0 + 16;
  int m0 = mt * 128 + rr0,     m1 = mt * 128 + rr1;
  const short* aB0 = Ab + ((size_t)(((m0 >> 6) + 2) * 66 + (m0 & 63) + 2) << 8) + cl8;
  const short* aB1 = Ab + ((size_t)(((m1 >> 6) + 2) * 66 + (m1 & 63) + 2) << 8) + cl8;
  const short* bB0 = Bb + (size_t)rr0 * 2304 + cl8;
  const short* bB1 = Bb + (size_t)rr1 * 2304 + cl8;

  int po = (quad ^ ((l16 >> 1) & 3)) * 8;   // read-side physical chunk offset (shorts)

  for (int kb0 = 0; kb0 < 36; ++kb0) {
    __syncthreads();
    #pragma unroll
    for (int u = 0; u < 2; ++u) {
      int kb = kb0 * 2 + u;
      int s = kb >> 3;
      int dy = (s * 11) >> 5;            // s/3 for s in 0..8
      int dx = s - 3 * dy;
      int offA = (kb & 7) * 32 - ((dy * 66 + dx) << 8);   // wave-uniform
      int offB = kb * 32;                                  // wave-uniform
      gload_lds16(aB0 + offA, As + u * 4096 + wave * 1024 + lane * 8);
      gload_lds16(bB0 + offB, Bs + u * 4096 + wave * 1024 + lane * 8);
      gload_lds16(aB1 + offA, As + u * 4096 + wave * 1024 + 512 + lane * 8);
      gload_lds16(bB1 + offB, Bs + u * 4096 + wave * 1024 + 512 + lane * 8);
    }
    __syncthreads();
    #pragma unroll
    for (int u = 0; u < 2; ++u) {
      short8 af[4], bfr[4];
      #pragma unroll
      for (int i = 0; i < 4; ++i)
        af[i] = *(const short8*)(As + u * 4096 + (wm * 64 + i * 16 + l16) * 32 + po);
      #pragma unroll
      for (int j = 0; j < 4; ++j)
        bfr[j] = *(const short8*)(Bs + u * 4096 + (wn * 64 + j * 16 + l16) * 32 + po);
      #pragma unroll
      for (int i = 0; i < 4; ++i)
        #pragma unroll
        for (int j = 0; j < 4; ++j)
          acc[i][j] = __builtin_amdgcn_mfma_f32_16x16x32_bf16(af[i], bfr[j], acc[i][j], 0, 0, 0);
    }
  }

  const float inv6 = 1.f / 6.f;
  #pragma unroll
  for (int i = 0; i < 4; ++i) {
    int mbase = mt * 128 + wm * 64 + i * 16 + quad * 4;
    #pragma unroll
    for (int j = 0; j < 4; ++j) {
      int n = nt * 128 + wn * 64 + j * 16 + l16;
      int r = n >> 6; int c = n & 63;
      int ry = r >> 2, rx = r & 3;
      #pragma unroll
      for (int reg = 0; reg < 4; ++reg) {
        int m = mbase + reg;
        int Qy = m >> 6, Qx = m & 63;
        out[(((size_t)b * 256 + 4 * Qy + ry) * 256 + (4 * Qx + rx)) * 64 + c]
            = acc[i][j][reg] * inv6;
      }
    }
  }
}

extern "C" void kernel_launch(void* const* d_in, const int* in_sizes, int n_in,
                              void* d_out, int out_size, void* d_ws, size_t ws_size,
                              hipStream_t stream) {
  const float* x           = (const float*)d_in[0];
  const float* theta_w     = (const float*)d_in[1];
  const float* theta_b     = (const float*)d_in[2];
  const float* theta_alpha = (const float*)d_in[3];
  const float* phi_w       = (const float*)d_in[4];
  const float* phi_b       = (const float*)d_in[5];
  const float* phi_alpha   = (const float*)d_in[6];
  const float* g_w         = (const float*)d_in[7];
  const float* g_b         = (const float*)d_in[8];
  const float* g_alpha     = (const float*)d_in[9];
  float* out = (float*)d_out;

  char* w = (char*)d_ws;
  size_t off = 0;
  auto alloc = [&](size_t bytes) { void* p = w + off; off += (bytes + 255) & ~255ull; return p; };
  short* g       = (short*)alloc(8ull * 4096 * 64 * 2);       // 4 MB (bf16)
  size_t thp_bytes = 8ull * 66 * 66 * 32 * 2;                 // 2.23 MB
  short* thetaPh = (short*)alloc(thp_bytes);
  short* thetaPl = (short*)alloc(thp_bytes);
  short* Bh      = (short*)alloc(8ull * 256 * 288 * 2);       // 1.18 MB
  short* Bl      = (short*)alloc(8ull * 256 * 288 * 2);
  size_t attnp_bytes = 8ull * 66 * 66 * 256 * 2;              // 17.8 MB
  short* attnp   = (short*)alloc(attnp_bytes);
  size_t bbf_full = 8ull * 1024 * 2304 * 2;                   // 37.7 MB
  bool full = (off + bbf_full) <= ws_size;
  short* Bbf = (short*)alloc(full ? bbf_full : bbf_full / 8);

  hipLaunchKernelGGL(k_pre, dim3(256 + 128), dim3(256), 0, stream,
                     x, theta_w, theta_b, theta_alpha, phi_w, phi_b, phi_alpha,
                     g_w, g_b, g_alpha, thetaPh, thetaPl, g, Bh, Bl);
  if (full) {
    hipLaunchKernelGGL(k_mid, dim3(48, BB), dim3(512), 0, stream,
                       g, Bbf, thetaPh, thetaPl, Bh, Bl, attnp, 1);
    hipLaunchKernelGGL(k_gemm, dim3(32, 8, BB), dim3(256), 0, stream, attnp, Bbf, out, 0);
  } else {
    hipLaunchKernelGGL(k_mid, dim3(48, BB), dim3(512), 0, stream,
                       g, Bbf, thetaPh, thetaPl, Bh, Bl, attnp, 0);
    for (int b = 0; b < BB; ++b) {
      hipLaunchKernelGGL(k_bgather, dim3(16, 1), dim3(256), 0, stream,
                         g + (size_t)b * 4096 * 64, Bbf);
      hipLaunchKernelGGL(k_gemm, dim3(32, 8, 1), dim3(256), 0, stream, attnp, Bbf, out, b);
    }
  }
}

// Round 16
// 374.450 us; speedup vs baseline: 1.1239x; 1.0093x over previous
//
#include <hip/hip_runtime.h>
#include <math.h>

// Problem constants: B=8, H=W=64, C=64, CI=32, SCALE=4, PATCH=3, N=256
#define BB 8

typedef __attribute__((ext_vector_type(8))) short short8;   // 8 x bf16 bits
typedef __attribute__((ext_vector_type(4))) float f32x4;

__device__ inline short f2bf(float x) {          // fp32 -> bf16 (RNE)
  unsigned u = __builtin_bit_cast(unsigned, x);
  u += 0x7fffu + ((u >> 16) & 1u);
  return (short)(u >> 16);
}
__device__ inline float bf2f(short h) {
  unsigned u = ((unsigned)(unsigned short)h) << 16;
  return __builtin_bit_cast(float, u);
}

__device__ inline void gload_lds16(const void* g, void* l) {
  __builtin_amdgcn_global_load_lds(
      (const __attribute__((address_space(1))) void*)g,
      (__attribute__((address_space(3))) void*)l, 16, 0, 0);
}

// Map ring-pixel index p (0..259) of a 66x66 frame to (row, col).
__device__ inline void ring_px(int p, int& r, int& cc) {
  if (p < 66) { r = 0; cc = p; }
  else if (p < 132) { r = 65; cc = p - 66; }
  else { int q = p - 132; r = 1 + (q >> 1); cc = (q & 1) ? 65 : 0; }
}

// ---------------- K1 (fused): blocks 0..255 = theta&g conv; 256..383 = phi+phin ----------------
__global__ __launch_bounds__(256) void k_pre(const float* __restrict__ x,
                          const float* __restrict__ theta_w, const float* __restrict__ theta_b,
                          const float* __restrict__ theta_alpha,
                          const float* __restrict__ phi_w, const float* __restrict__ phi_b,
                          const float* __restrict__ phi_alpha,
                          const float* __restrict__ g_w, const float* __restrict__ g_b,
                          const float* __restrict__ g_alpha,
                          short* __restrict__ thetaPh, short* __restrict__ thetaPl,
                          short* __restrict__ gOut,
                          short* __restrict__ Bh, short* __restrict__ Bl) {
  __shared__ __align__(16) float spool[14528];
  int tid = threadIdx.x;
  if (blockIdx.x < 256) {
    // ======== theta & g path ========
    int bid = blockIdx.x;
    int b = bid >> 5, pg = bid & 31;
    int px0 = pg * 128;
    // zero thetaP ring: 1040 short8-chunks per array per batch
    if (tid <= 32) {
      int c = pg + 32 * tid;
      if (c < 1040) {
        int p = c >> 2, off = (c & 3) * 8;
        int r, cc; ring_px(p, r, cc);
        size_t ad = ((size_t)(b * 66 + r) * 66 + cc) * 32 + off;
        short8 z = (short8)0;
        *(short8*)(thetaPh + ad) = z;
        *(short8*)(thetaPl + ad) = z;
      }
    }
    float* gw = spool;              // 64*64
    float* tw = spool + 4096;       // 64*32
    float* xs = spool + 6144;       // 64*128
    float* gb_s = spool + 14336; float* ga_s = spool + 14400;
    float* tb_s = spool + 14464; float* ta_s = spool + 14496;
    for (int idx = tid; idx < 1024; idx += 256) ((float4*)gw)[idx] = ((const float4*)g_w)[idx];
    for (int idx = tid; idx < 512; idx += 256)  ((float4*)tw)[idx] = ((const float4*)theta_w)[idx];
    if (tid < 64) { gb_s[tid] = g_b[tid]; ga_s[tid] = g_alpha[tid]; }
    else if (tid < 96) { tb_s[tid - 64] = theta_b[tid - 64]; ta_s[tid - 64] = theta_alpha[tid - 64]; }
    {
      int p = tid >> 1, half = tid & 1;
      const float* xp = x + ((size_t)b * 4096 + px0 + p) * 64 + half * 32;
      #pragma unroll
      for (int i = 0; i < 8; ++i) {
        float4 v = ((const float4*)xp)[i];
        int k = half * 32 + i * 4;
        xs[(k + 0) * 128 + p] = v.x; xs[(k + 1) * 128 + p] = v.y;
        xs[(k + 2) * 128 + p] = v.z; xs[(k + 3) * 128 + p] = v.w;
      }
    }
    __syncthreads();
    int pp = tid >> 2, q = tid & 3;
    float accg[2][16], acct[2][8];
    #pragma unroll
    for (int c = 0; c < 16; ++c) { float bv = gb_s[q * 16 + c]; accg[0][c] = bv; accg[1][c] = bv; }
    #pragma unroll
    for (int c = 0; c < 8; ++c)  { float bv = tb_s[q * 8 + c];  acct[0][c] = bv; acct[1][c] = bv; }
    for (int k = 0; k < 64; ++k) {
      float x0 = xs[k * 128 + 2 * pp], x1 = xs[k * 128 + 2 * pp + 1];
      const float* gwr = gw + k * 64 + q * 16;
      const float* twr = tw + k * 32 + q * 8;
      #pragma unroll
      for (int c = 0; c < 16; ++c) { float wv = gwr[c]; accg[0][c] += x0 * wv; accg[1][c] += x1 * wv; }
      #pragma unroll
      for (int c = 0; c < 8; ++c)  { float wv = twr[c]; acct[0][c] += x0 * wv; acct[1][c] += x1 * wv; }
    }
    #pragma unroll
    for (int e = 0; e < 2; ++e) {
      int px = px0 + 2 * pp + e;
      // g output bf16 (consumed only by gather, which converted anyway)
      short* gp = gOut + ((size_t)(b * 4096 + px)) * 64 + q * 16;
      short8 gv0, gv1;
      #pragma unroll
      for (int c = 0; c < 16; ++c) {
        float v = accg[e][c];
        float a = ga_s[q * 16 + c];
        v = v >= 0.f ? v : a * v;
        short hb = f2bf(v);
        if (c < 8) gv0[c] = hb; else gv1[c - 8] = hb;
      }
      *(short8*)(gp) = gv0;
      *(short8*)(gp + 8) = gv1;
      int h = px >> 6, w = px & 63;
      size_t off = ((size_t)(b * 66 + h + 1) * 66 + (w + 1)) * 32 + q * 8;
      short8 hv, lv;
      #pragma unroll
      for (int c = 0; c < 8; ++c) {
        float t = acct[e][c];
        float a = ta_s[q * 8 + c];
        float v = t >= 0.f ? t : a * t;
        short hi = f2bf(v);
        hv[c] = hi;
        lv[c] = f2bf(v - bf2f(hi));
      }
      *(short8*)(thetaPh + off) = hv;
      *(short8*)(thetaPl + off) = lv;
    }
  } else {
    // ======== phi + phin path: one block per (b, i-row), halo recomputed ========
    int bid = blockIdx.x - 256;
    int b = bid >> 4, irow = bid & 15;
    float* pw   = spool;            // 64*32
    float* pb   = spool + 2048;     // 32
    float* pa   = spool + 2080;     // 32
    float* ph_s = spool + 2112;     // 48*33
    float* ss2  = spool + 3696;     // 48
    float* ssp  = spool + 3744;     // 192
    for (int idx = tid; idx < 512; idx += 256) ((float4*)pw)[idx] = ((const float4*)phi_w)[idx];
    if (tid < 32) { pb[tid] = phi_b[tid]; pa[tid] = phi_alpha[tid]; }
    __syncthreads();
    // conv: threads t = lr*64 + j*4 + cg  (lr<3, j<16, cg<4 -> 8 channels each)
    if (tid < 192) {
      int lr = tid >> 6, j = (tid >> 2) & 15, cg = tid & 3;
      int i2 = irow + lr - 1;
      float acc8[8];
      float sum2 = 0.f;
      if (i2 >= 0 && i2 < 16) {
        #pragma unroll
        for (int c = 0; c < 8; ++c) acc8[c] = pb[cg * 8 + c];
        const float* xb = x + (size_t)b * 4096 * 64;
        const float* p00 = xb + ((size_t)(4 * i2 + 1) * 64 + (4 * j + 1)) * 64;
        for (int kq = 0; kq < 16; ++kq) {
          float4 a = ((const float4*)p00)[kq];
          float4 bq = ((const float4*)(p00 + 64))[kq];
          float4 cq = ((const float4*)(p00 + 4096))[kq];
          float4 dq = ((const float4*)(p00 + 4160))[kq];
          float xv[4] = {0.25f * (a.x + bq.x + cq.x + dq.x), 0.25f * (a.y + bq.y + cq.y + dq.y),
                         0.25f * (a.z + bq.z + cq.z + dq.z), 0.25f * (a.w + bq.w + cq.w + dq.w)};
          #pragma unroll
          for (int e = 0; e < 4; ++e) {
            const float* pwr = pw + (kq * 4 + e) * 32 + cg * 8;
            #pragma unroll
            for (int c = 0; c < 8; ++c) acc8[c] += xv[e] * pwr[c];
          }
        }
        #pragma unroll
        for (int c = 0; c < 8; ++c) {
          float v = acc8[c];
          v = v >= 0.f ? v : pa[cg * 8 + c] * v;
          ph_s[(lr * 16 + j) * 33 + cg * 8 + c] = v;
          sum2 += v * v;
        }
      } else {
        #pragma unroll
        for (int c = 0; c < 8; ++c) ph_s[(lr * 16 + j) * 33 + cg * 8 + c] = 0.f;
      }
      ssp[tid] = sum2;
    }
    __syncthreads();
    if (tid < 48) ss2[tid] = ssp[tid*4] + ssp[tid*4+1] + ssp[tid*4+2] + ssp[tid*4+3];
    __syncthreads();
    // write: thread = j*16 + u, u<9 = shift s
    int j = tid >> 4, u = tid & 15;
    if (u < 9) {
      float nn = 0.f;
      #pragma unroll
      for (int lr = 0; lr < 3; ++lr) {
        int i2 = irow + lr - 1;
        if (i2 < 0 || i2 > 15) continue;
        #pragma unroll
        for (int dj = 0; dj < 3; ++dj) {
          int pj = j + dj - 1;
          if (pj >= 0 && pj < 16) nn += ss2[lr * 16 + pj];
        }
      }
      float scale = 1.f / fmaxf(sqrtf(nn), 1e-6f);
      int lr = u / 3, dj = u % 3;
      int i2 = irow + lr - 1, pj = j + dj - 1;
      bool ok = (i2 >= 0 && i2 < 16 && pj >= 0 && pj < 16);
      size_t base = ((size_t)(b * 256 + irow * 16 + j)) * 288 + u * 32;
      #pragma unroll
      for (int q8 = 0; q8 < 4; ++q8) {
        short8 hv, lv;
        #pragma unroll
        for (int c = 0; c < 8; ++c) {
          float v = ok ? ph_s[(lr * 16 + pj) * 33 + q8 * 8 + c] * scale : 0.f;
          short hi = f2bf(v);
          hv[c] = hi;
          lv[c] = f2bf(v - bf2f(hi));
        }
        *(short8*)(Bh + base + q8 * 8) = hv;
        *(short8*)(Bl + base + q8 * 8) = lv;
      }
    }
  }
}

// ---------------- standalone K4a (fallback path only): gather g (bf16) -> Bbf ----------------
__global__ __launch_bounds__(256) void k_bgather(const short* __restrict__ g,
                                                 short* __restrict__ Bbf) {
  int r = blockIdx.x;              // 0..15 = (ry,rx)
  int bl = blockIdx.y;
  int ry = r >> 2, rx = r & 3;
  int t = threadIdx.x;
  int wv = t >> 6, l = t & 63;
  int jj = t >> 4, c4 = (t & 15) * 4;
  __shared__ short tile[256 * 66];
  const short* gb = g + (size_t)bl * 4096 * 64;
  for (int s = 0; s < 9; ++s) {
    int dy = s / 3, dx = s % 3;
    {
      int col = 4 * jj + rx + 4 * dx - 4;
      #pragma unroll
      for (int i2 = 0; i2 < 16; ++i2) {
        int row = 4 * i2 + ry + 4 * dy - 4;
        short4 v = make_short4(0, 0, 0, 0);
        if (row >= 0 && row < 64 && col >= 0 && col < 64)
          v = *(const short4*)(gb + (((size_t)row << 6) + col) * 64 + c4);
        int ij = i2 * 16 + jj;
        tile[ij * 66 + c4 + 0] = v.x;
        tile[ij * 66 + c4 + 1] = v.y;
        tile[ij * 66 + c4 + 2] = v.z;
        tile[ij * 66 + c4 + 3] = v.w;
      }
    }
    __syncthreads();
    #pragma unroll
    for (int cc = 0; cc < 16; ++cc) {
      int c = cc * 4 + wv;
      int n = r * 64 + c;
      unsigned* dstrow = (unsigned*)(Bbf + ((size_t)bl * 1024 + n) * 2304 + s * 256);
      #pragma unroll
      for (int half = 0; half < 2; ++half) {
        int ij0 = half * 128 + 2 * l;
        unsigned v = (unsigned)(unsigned short)tile[ij0 * 66 + c]
                   | ((unsigned)(unsigned short)tile[(ij0 + 1) * 66 + c] << 16);
        dstrow[half * 64 + l] = v;
      }
    }
    __syncthreads();
  }
}

// ---------------- K_mid (fused): blocks x<16 = bgather; x>=16 = scores+softmax ----------------
// Score path v2: (1) Ph window (4x66 pixels x 32ch = union of all 9 shifts for this block's
// 128 A-rows) staged ONCE; (2) Bsh/Bsl use the R6-proven chunk-XOR swizzle (phys = logical
// ^ ((row>>1)&3)) applied on the global source + inverted on the fragment read.
__global__ __launch_bounds__(512) void k_mid(const short* __restrict__ g,
                                             short* __restrict__ Bbf,
                                             const short* __restrict__ thetaPh,
                                             const short* __restrict__ thetaPl,
                                             const short* __restrict__ Bh,
                                             const short* __restrict__ Bl,
                                             short* __restrict__ attnp,
                                             int doGather) {
  __shared__ __align__(16) short smem[32768];
  int tid = threadIdx.x;
  int b = blockIdx.y;
  if (blockIdx.x < 16) {
    // ======== gather path (256 active threads; 512-thread block for uniformity) ========
    if (!doGather) return;
    int r = blockIdx.x, bl = b;
    int ry = r >> 2, rx = r & 3;
    short* tile = smem;            // 256*66 shorts = 33 KB
    const short* gb = g + (size_t)bl * 4096 * 64;
    for (int s = 0; s < 9; ++s) {
      int dy = s / 3, dx = s % 3;
      if (tid < 256) {
        int jj = tid >> 4, c4 = (tid & 15) * 4;
        int col = 4 * jj + rx + 4 * dx - 4;
        #pragma unroll
        for (int i2 = 0; i2 < 16; ++i2) {
          int row = 4 * i2 + ry + 4 * dy - 4;
          short4 v = make_short4(0, 0, 0, 0);
          if (row >= 0 && row < 64 && col >= 0 && col < 64)
            v = *(const short4*)(gb + (((size_t)row << 6) + col) * 64 + c4);
          int ij = i2 * 16 + jj;
          tile[ij * 66 + c4 + 0] = v.x;
          tile[ij * 66 + c4 + 1] = v.y;
          tile[ij * 66 + c4 + 2] = v.z;
          tile[ij * 66 + c4 + 3] = v.w;
        }
      }
      __syncthreads();
      if (tid < 256) {
        int wv = tid >> 6, l = tid & 63;
        #pragma unroll
        for (int cc = 0; cc < 16; ++cc) {
          int c = cc * 4 + wv;
          int n = r * 64 + c;
          unsigned* dstrow = (unsigned*)(Bbf + ((size_t)bl * 1024 + n) * 2304 + s * 256);
          #pragma unroll
          for (int half = 0; half < 2; ++half) {
            int ij0 = half * 128 + 2 * l;
            unsigned v = (unsigned)(unsigned short)tile[ij0 * 66 + c]
                       | ((unsigned)(unsigned short)tile[(ij0 + 1) * 66 + c] << 16);
            dstrow[half * 64 + l] = v;
          }
        }
      }
      __syncthreads();
    }
    return;
  }
  // ======== scores + softmax path ========
  int mt = blockIdx.x - 16;        // 0..31
  // zero attnp ring: 8320 short8-chunks per batch
  {
    int c = mt + 32 * tid;
    if (c < 8320) {
      int p = c >> 5, off = (c & 31) * 8;
      int r, cc; ring_px(p, r, cc);
      *(short8*)(attnp + ((size_t)(b * 66 + r) * 66 + cc) * 256 + off) = (short8)0;
    }
  }
  int w = tid >> 6, lane = tid & 63;
  int wm = w >> 2, wn = w & 3;
  int quad = lane >> 4, l16 = lane & 15;

  short* Wph = smem;                     // 8448 shorts: Ph window [4 rows][66 px][32 ch]
  short* Asl = smem + 8448;              // 4096: Pl tile (per round)
  short* Bsh = smem + 12544;             // 8192 (swizzled)
  short* Bsl = smem + 20736;             // 8192 (swizzled)
  float* wred = (float*)(smem + 28928);  // 512 floats

  f32x4 acc[4][4];
  #pragma unroll
  for (int i = 0; i < 4; ++i)
    #pragma unroll
    for (int j = 0; j < 4; ++j) acc[i][j] = (f32x4)0.f;

  int ar = w * 16 + (lane >> 2);
  int am = mt * 128 + ar;
  int aQy = am >> 6, aQx = am & 63;
  int achunk = (lane & 3) * 8;

  // Hoisted: stage the Ph window (pixel rows mt*2 .. mt*2+3, cols 0..65) once.
  // 4*66*32 = 8448 shorts = 1056 x 16B granules; contiguous in global (row-major).
  {
    const short* wh = thetaPh + (size_t)(b * 66 + mt * 2) * 66 * 32;
    gload_lds16(wh + (size_t)tid * 8, Wph + tid * 8);
    gload_lds16(wh + (size_t)(tid + 512) * 8, Wph + (tid + 512) * 8);
    if (tid < 32)
      gload_lds16(wh + (size_t)(tid + 1024) * 8, Wph + (tid + 1024) * 8);
  }
  int cl8b = ((lane & 3) ^ ((lane >> 3) & 3)) * 8;   // B staging: logical col (swizzled src)
  int pob  = (quad ^ ((l16 >> 1) & 3)) * 8;          // B read: physical chunk offset

  for (int s = 0; s < 9; ++s) {
    int di = s / 3, dj = s % 3;
    __syncthreads();
    // Pl tile for this shift (pass-2 A operand), unswizzled as before
    gload_lds16(thetaPl + ((size_t)(b * 66 + aQy + di) * 66 + (aQx + dj)) * 32 + achunk,
                Asl + w * 512 + lane * 8);
    #pragma unroll
    for (int p = 0; p < 2; ++p) {
      int nl = w * 32 + p * 16 + (lane >> 2);
      size_t boff = ((size_t)(b * 256 + nl)) * 288 + s * 32 + cl8b;
      gload_lds16(Bh + boff, Bsh + w * 1024 + p * 512 + lane * 8);
      gload_lds16(Bl + boff, Bsl + w * 1024 + p * 512 + lane * 8);
    }
    __syncthreads();
    #pragma unroll
    for (int pass = 0; pass < 3; ++pass) {
      const short* Bsrc = (pass == 1) ? Bsl : Bsh;
      short8 af[4], bfr[4];
      if (pass < 2) {
        #pragma unroll
        for (int i = 0; i < 4; ++i)
          af[i] = *(const short8*)(Wph + ((wm + di) * 66 + i * 16 + l16 + dj) * 32 + quad * 8);
      } else {
        #pragma unroll
        for (int i = 0; i < 4; ++i)
          af[i] = *(const short8*)(Asl + (wm * 64 + i * 16 + l16) * 32 + quad * 8);
      }
      #pragma unroll
      for (int j = 0; j < 4; ++j)
        bfr[j] = *(const short8*)(Bsrc + (wn * 64 + j * 16 + l16) * 32 + pob);
      #pragma unroll
      for (int i = 0; i < 4; ++i)
        #pragma unroll
        for (int j = 0; j < 4; ++j)
          acc[i][j] = __builtin_amdgcn_mfma_f32_16x16x32_bf16(af[i], bfr[j], acc[i][j], 0, 0, 0);
    }
  }

  float rmax[4][4];
  #pragma unroll
  for (int i = 0; i < 4; ++i)
    #pragma unroll
    for (int reg = 0; reg < 4; ++reg) {
      float m = -1e30f;
      #pragma unroll
      for (int j = 0; j < 4; ++j) m = fmaxf(m, acc[i][j][reg]);
      #pragma unroll
      for (int off = 1; off < 16; off <<= 1) m = fmaxf(m, __shfl_xor(m, off));
      rmax[i][reg] = m;
    }
  if (l16 == 0) {
    #pragma unroll
    for (int i = 0; i < 4; ++i)
      #pragma unroll
      for (int reg = 0; reg < 4; ++reg)
        wred[(wm * 64 + i * 16 + quad * 4 + reg) * 4 + wn] = rmax[i][reg];
  }
  __syncthreads();
  #pragma unroll
  for (int i = 0; i < 4; ++i)
    #pragma unroll
    for (int reg = 0; reg < 4; ++reg) {
      int r = wm * 64 + i * 16 + quad * 4 + reg;
      rmax[i][reg] = fmaxf(fmaxf(wred[r * 4 + 0], wred[r * 4 + 1]),
                           fmaxf(wred[r * 4 + 2], wred[r * 4 + 3]));
    }
  __syncthreads();
  float rsum[4][4];
  #pragma unroll
  for (int i = 0; i < 4; ++i)
    #pragma unroll
    for (int reg = 0; reg < 4; ++reg) {
      float s = 0.f;
      #pragma unroll
      for (int j = 0; j < 4; ++j) {
        float e = expf((acc[i][j][reg] - rmax[i][reg]) * 10.f);
        acc[i][j][reg] = e;
        s += e;
      }
      #pragma unroll
      for (int off = 1; off < 16; off <<= 1) s += __shfl_xor(s, off);
      rsum[i][reg] = s;
    }
  if (l16 == 0) {
    #pragma unroll
    for (int i = 0; i < 4; ++i)
      #pragma unroll
      for (int reg = 0; reg < 4; ++reg)
        wred[(wm * 64 + i * 16 + quad * 4 + reg) * 4 + wn] = rsum[i][reg];
  }
  __syncthreads();
  #pragma unroll
  for (int i = 0; i < 4; ++i)
    #pragma unroll
    for (int reg = 0; reg < 4; ++reg) {
      int r = wm * 64 + i * 16 + quad * 4 + reg;
      float tot = wred[r * 4 + 0] + wred[r * 4 + 1] + wred[r * 4 + 2] + wred[r * 4 + 3];
      rsum[i][reg] = 1.f / tot;
    }
  __syncthreads();
  #pragma unroll
  for (int i = 0; i < 4; ++i)
    #pragma unroll
    for (int reg = 0; reg < 4; ++reg) {
      int r = wm * 64 + i * 16 + quad * 4 + reg;
      #pragma unroll
      for (int j = 0; j < 4; ++j)
        smem[r * 256 + wn * 64 + j * 16 + l16] = f2bf(acc[i][j][reg] * rsum[i][reg]);
    }
  __syncthreads();
  {
    int r2 = tid >> 2, c2 = (tid & 3) * 64;
    int m2 = mt * 128 + r2;
    int Qy = m2 >> 6, Qx = m2 & 63;
    short8* dst = (short8*)(attnp + ((size_t)(b * 66 + Qy + 1) * 66 + (Qx + 1)) * 256 + c2);
    #pragma unroll
    for (int q = 0; q < 8; ++q) dst[q] = *(const short8*)(smem + r2 * 256 + c2 + q * 8);
  }
}

// ---------------- K4b: deconv GEMM — R6 version (best measured: 183us, 0 conflicts) ---------
// 2-barrier BK=64 schedule + conflict-free chunk swizzle + hoisted base pointers.
// All schedule deviations measured (dbuf64 R4, BK32-2ph R5, BK96 R7, vmcnt-ring R8, grid
// split R9) regress; this is the structure optimum. Single full-batch launch.
__global__ __launch_bounds__(256) void k_gemm(const short* __restrict__ attnp,
                                              const short* __restrict__ Bbf,
                                              float* __restrict__ out,
                                              int b0) {
  int lid = blockIdx.x + 32 * blockIdx.y + 256 * blockIdx.z;
  int nwg = 256 * gridDim.z;
  int chunk = nwg >> 3;
  int swz = (lid & 7) * chunk + (lid >> 3);
  int mt = swz & 31;               // 0..31
  int nt = (swz >> 5) & 7;         // 0..7
  int bl = swz >> 8;
  int b = b0 + bl;
  int tid = threadIdx.x;
  int wave = tid >> 6, lane = tid & 63;
  int wm = wave >> 1, wn = wave & 1;
  int quad = lane >> 4, l16 = lane & 15;

  __shared__ __align__(16) short As[8192];   // 2 u-chunks x 128x32, swizzled
  __shared__ __align__(16) short Bs[8192];

  f32x4 acc[4][4];
  #pragma unroll
  for (int i = 0; i < 4; ++i)
    #pragma unroll
    for (int j = 0; j < 4; ++j) acc[i][j] = (f32x4)0.f;

  const short* Ab = attnp + (size_t)b * 66 * 66 * 256;
  const short* Bb = Bbf + (size_t)bl * 1024 * 2304 + (size_t)(nt * 128) * 2304;

  // Staging map: row = wave*32 + t*16 + (lane>>2), phys chunk = lane&3.
  // Swizzle: logical chunk = phys ^ ((row>>1)&3) = (lane&3) ^ ((lane>>3)&3).
  int larow = lane >> 2;
  int cl8 = ((lane & 3) ^ ((lane >> 3) & 3)) * 8;   // logical col offset (shorts)

  // Hoisted per-thread base pointers (t=0,1). Per-iter offsets are wave-uniform.
  int rr0 = wave * 32 + larow, rr1 = rr0 + 16;
  int m0 = mt * 128 + rr0,     m1 = mt * 128 + rr1;
  const short* aB0 = Ab + ((size_t)(((m0 >> 6) + 2) * 66 + (m0 & 63) + 2) << 8) + cl8;
  const short* aB1 = Ab + ((size_t)(((m1 >> 6) + 2) * 66 + (m1 & 63) + 2) << 8) + cl8;
  const short* bB0 = Bb + (size_t)rr0 * 2304 + cl8;
  const short* bB1 = Bb + (size_t)rr1 * 2304 + cl8;

  int po = (quad ^ ((l16 >> 1) & 3)) * 8;   // read-side physical chunk offset (shorts)

  for (int kb0 = 0; kb0 < 36; ++kb0) {
    __syncthreads();
    #pragma unroll
    for (int u = 0; u < 2; ++u) {
      int kb = kb0 * 2 + u;
      int s = kb >> 3;
      int dy = (s * 11) >> 5;            // s/3 for s in 0..8
      int dx = s - 3 * dy;
      int offA = (kb & 7) * 32 - ((dy * 66 + dx) << 8);   // wave-uniform
      int offB = kb * 32;                                  // wave-uniform
      gload_lds16(aB0 + offA, As + u * 4096 + wave * 1024 + lane * 8);
      gload_lds16(bB0 + offB, Bs + u * 4096 + wave * 1024 + lane * 8);
      gload_lds16(aB1 + offA, As + u * 4096 + wave * 1024 + 512 + lane * 8);
      gload_lds16(bB1 + offB, Bs + u * 4096 + wave * 1024 + 512 + lane * 8);
    }
    __syncthreads();
    #pragma unroll
    for (int u = 0; u < 2; ++u) {
      short8 af[4], bfr[4];
      #pragma unroll
      for (int i = 0; i < 4; ++i)
        af[i] = *(const short8*)(As + u * 4096 + (wm * 64 + i * 16 + l16) * 32 + po);
      #pragma unroll
      for (int j = 0; j < 4; ++j)
        bfr[j] = *(const short8*)(Bs + u * 4096 + (wn * 64 + j * 16 + l16) * 32 + po);
      #pragma unroll
      for (int i = 0; i < 4; ++i)
        #pragma unroll
        for (int j = 0; j < 4; ++j)
          acc[i][j] = __builtin_amdgcn_mfma_f32_16x16x32_bf16(af[i], bfr[j], acc[i][j], 0, 0, 0);
    }
  }

  const float inv6 = 1.f / 6.f;
  #pragma unroll
  for (int i = 0; i < 4; ++i) {
    int mbase = mt * 128 + wm * 64 + i * 16 + quad * 4;
    #pragma unroll
    for (int j = 0; j < 4; ++j) {
      int n = nt * 128 + wn * 64 + j * 16 + l16;
      int r = n >> 6; int c = n & 63;
      int ry = r >> 2, rx = r & 3;
      #pragma unroll
      for (int reg = 0; reg < 4; ++reg) {
        int m = mbase + reg;
        int Qy = m >> 6, Qx = m & 63;
        out[(((size_t)b * 256 + 4 * Qy + ry) * 256 + (4 * Qx + rx)) * 64 + c]
            = acc[i][j][reg] * inv6;
      }
    }
  }
}

extern "C" void kernel_launch(void* const* d_in, const int* in_sizes, int n_in,
                              void* d_out, int out_size, void* d_ws, size_t ws_size,
                              hipStream_t stream) {
  const float* x           = (const float*)d_in[0];
  const float* theta_w     = (const float*)d_in[1];
  const float* theta_b     = (const float*)d_in[2];
  const float* theta_alpha = (const float*)d_in[3];
  const float* phi_w       = (const float*)d_in[4];
  const float* phi_b       = (const float*)d_in[5];
  const float* phi_alpha   = (const float*)d_in[6];
  const float* g_w         = (const float*)d_in[7];
  const float* g_b         = (const float*)d_in[8];
  const float* g_alpha     = (const float*)d_in[9];
  float* out = (float*)d_out;

  char* w = (char*)d_ws;
  size_t off = 0;
  auto alloc = [&](size_t bytes) { void* p = w + off; off += (bytes + 255) & ~255ull; return p; };
  short* g       = (short*)alloc(8ull * 4096 * 64 * 2);       // 4 MB (bf16)
  size_t thp_bytes = 8ull * 66 * 66 * 32 * 2;                 // 2.23 MB
  short* thetaPh = (short*)alloc(thp_bytes);
  short* thetaPl = (short*)alloc(thp_bytes);
  short* Bh      = (short*)alloc(8ull * 256 * 288 * 2);       // 1.18 MB
  short* Bl      = (short*)alloc(8ull * 256 * 288 * 2);
  size_t attnp_bytes = 8ull * 66 * 66 * 256 * 2;              // 17.8 MB
  short* attnp   = (short*)alloc(attnp_bytes);
  size_t bbf_full = 8ull * 1024 * 2304 * 2;                   // 37.7 MB
  bool full = (off + bbf_full) <= ws_size;
  short* Bbf = (short*)alloc(full ? bbf_full : bbf_full / 8);

  hipLaunchKernelGGL(k_pre, dim3(256 + 128), dim3(256), 0, stream,
                     x, theta_w, theta_b, theta_alpha, phi_w, phi_b, phi_alpha,
                     g_w, g_b, g_alpha, thetaPh, thetaPl, g, Bh, Bl);
  if (full) {
    hipLaunchKernelGGL(k_mid, dim3(48, BB), dim3(512), 0, stream,
                       g, Bbf, thetaPh, thetaPl, Bh, Bl, attnp, 1);
    hipLaunchKernelGGL(k_gemm, dim3(32, 8, BB), dim3(256), 0, stream, attnp, Bbf, out, 0);
  } else {
    hipLaunchKernelGGL(k_mid, dim3(48, BB), dim3(512), 0, stream,
                       g, Bbf, thetaPh, thetaPl, Bh, Bl, attnp, 0);
    for (int b = 0; b < BB; ++b) {
      hipLaunchKernelGGL(k_bgather, dim3(16, 1), dim3(256), 0, stream,
                         g + (size_t)b * 4096 * 64, Bbf);
      hipLaunchKernelGGL(k_gemm, dim3(32, 8, 1), dim3(256), 0, stream, attnp, Bbf, out, b);
    }
  }
}